// Round 6
// baseline (8836.810 us; speedup 1.0000x reference)
//
#include <hip/hip_runtime.h>
#include <hip/hip_bf16.h>
#include <cstdint>
#include <cstddef>

// 3-layer LSTM (T=128, B=256, IN=512, H=1024/1024/512) — persistent kernel, round 6.
// vs round 5 (8.54 ms, latency-bound: MfmaUtil 6.5%, VALUBusy 19.5%, no pipe busy):
//  - LAYER-SPECIALIZED block groups: blk 0..127 -> l2 only (32 cols, 128 KB LDS);
//    blk 128..255 -> l1 (32 cols, 96 KB) + l3 (16 cols, 48 KB). Layers run
//    concurrently per phase; per-block chunk chain 160 -> 64/96.
//  - 2 N-tiles per block share each A-load: broadcast traffic halves (~320 MB/step).
//  - 8-wide h/x slabs: A-fragment = ONE global_load_dwordx4 (was 2).
//  - l3 uses standard 16-col UPB=4 pack (zero-slab hack removed).
//  - K-loop ring unchanged from round 5 (depth 4, unroll 4 — proven no-spill).

typedef __attribute__((ext_vector_type(8))) short short8;
typedef __attribute__((ext_vector_type(4))) short short4v;
typedef __attribute__((ext_vector_type(4))) float floatx4;

#define NBLK 256
#define NTHR 1024

// ---------------- helpers ----------------
__device__ __forceinline__ float fsig(float x) {
    x = fminf(fmaxf(x, -30.f), 30.f);
    return 1.f / (1.f + __expf(-x));
}
__device__ __forceinline__ float ftanh(float x) {
    x = fminf(fmaxf(x, -15.f), 15.f);
    float e = __expf(2.f * x);
    return (e - 1.f) / (e + 1.f);
}

// Two-level monotonic barrier (round-5, proven): groups of 32 blocks arrive on
// padded per-group counters; closers bump master; 8th closer bumps gen.
__device__ __forceinline__ void grid_sync(int* sy) {
    __syncthreads();
    if (threadIdx.x == 0) {
        __threadfence();
        int* gen = sy + 576;
        int g = __hip_atomic_load(gen, __ATOMIC_RELAXED, __HIP_MEMORY_SCOPE_AGENT);
        int grp = blockIdx.x & 7;
        int a = __hip_atomic_fetch_add(sy + grp * 64, 1, __ATOMIC_ACQ_REL, __HIP_MEMORY_SCOPE_AGENT);
        if (((a + 1) & 31) == 0) {
            int m = __hip_atomic_fetch_add(sy + 512, 1, __ATOMIC_ACQ_REL, __HIP_MEMORY_SCOPE_AGENT);
            if (((m + 1) & 7) == 0)
                __hip_atomic_fetch_add(gen, 1, __ATOMIC_RELEASE, __HIP_MEMORY_SCOPE_AGENT);
        }
        while (__hip_atomic_load(gen, __ATOMIC_ACQUIRE, __HIP_MEMORY_SCOPE_AGENT) == g)
            __builtin_amdgcn_s_sleep(2);
        __threadfence();
    }
    __syncthreads();
}

// ---------------- pack kernels ----------------
// Frag-ordered weight pack: dst[tile][kc][slot] of short8, 16 cols per tile.
// slot = lane: du=slot&3, g=(slot>>2)&3, ksub=slot>>4. unit = tile*4+du.
template<int K1, int K2, int H>
__global__ void pack_frag_kernel(const float* __restrict__ Wih,
                                 const float* __restrict__ Whh,
                                 __hip_bfloat16* __restrict__ dst) {
    constexpr int NK = (K1 + K2) / 32;
    constexpr int NTT = H / 4;          // number of 16-col tiles
    int idx = blockIdx.x * 256 + threadIdx.x;
    if (idx >= NTT * NK * 64) return;
    int slot = idx & 63;
    int kc = (idx >> 6) % NK;
    int b = idx / (64 * NK);
    int du = slot & 3, g = (slot >> 2) & 3, ksub = slot >> 4;
    int unit = b * 4 + du;
    int j = g * H + unit;
    int k0 = kc * 32 + ksub * 8;
    __hip_bfloat16 tmp[8];
#pragma unroll
    for (int e = 0; e < 8; ++e) {
        int k = k0 + e;
        float v = (k < K1) ? Wih[(size_t)j * K1 + k] : Whh[(size_t)j * K2 + (k - K1)];
        tmp[e] = __float2bfloat16(v);
    }
    *(short8*)(dst + (size_t)idx * 8) = *(short8*)tmp;
}

__global__ void pack_bias_kernel(const float* __restrict__ a,
                                 const float* __restrict__ b,
                                 int n, float* __restrict__ out) {
    int i = blockIdx.x * 256 + threadIdx.x;
    if (i < n) out[i] = a[i] + b[i];
}

// x[t][row][512] fp32 -> xs[t][s 0..63][row][8] bf16 (8-wide slabs).
__global__ void x_to_slab_kernel(const float* __restrict__ x,
                                 __hip_bfloat16* __restrict__ xs) {
    int idx = blockIdx.x * 256 + threadIdx.x;
    int j   = idx & 7;
    int row = (idx >> 3) & 255;
    int s   = (idx >> 11) & 63;
    int t   = idx >> 17;
    xs[idx] = __float2bfloat16(x[((size_t)(t * 256 + row)) * 512 + s * 8 + j]);
}

__global__ void zero_f32_kernel(float* p, int n) {
    int i = blockIdx.x * 256 + threadIdx.x;
    if (i < n) p[i] = 0.f;
}

__global__ void zero_i32_kernel(int* p, int n) {
    int i = blockIdx.x * 256 + threadIdx.x;
    if (i < n) p[i] = 0;
}

// ---------------- A-fragment loaders ----------------
// 8-wide slabs: one 16-B load. base pre-offset by ksub*2048 + row*8.
__device__ __forceinline__ short8 afrag8(const __hip_bfloat16* __restrict__ base, int k) {
    return *(const short8*)(base + (size_t)k * 8192);
}
// 4-wide slabs (h3): two 8-B loads. base pre-offset by ksub*2048 + row*4.
__device__ __forceinline__ short8 afrag4(const __hip_bfloat16* __restrict__ base, int k) {
    const __hip_bfloat16* p = base + (size_t)k * 8192;
    short4v lo = *(const short4v*)p;
    short4v hi = *(const short4v*)(p + 1024);
    return (short8){lo.x, lo.y, lo.z, lo.w, hi.x, hi.y, hi.z, hi.w};
}

// ---------------- per-layer GEMM + fused cell ----------------
// Wave = 16-row M-tile; block owns NT 16-col tiles sharing each A-load.
// B-frags from LDS (tile ti at bslot0 + ti*TSTR + kc*64). Ring depth 4, unroll 4.
template<int NK1, int NK2, bool A2W4, int NT, int H, int TSTR>
__device__ __forceinline__ void run_layer(
    const short8* __restrict__ ldsw, int bslot0,
    const __hip_bfloat16* __restrict__ A1, const __hip_bfloat16* __restrict__ A2,
    const float (&bl)[NT],
    __hip_bfloat16* __restrict__ hs, int slab,
    float (&creg)[NT][4], int tbase, int lane, int wave,
    bool fin, float* __restrict__ ho, float* __restrict__ co)
{
    constexpr int NK = NK1 + NK2;
    constexpr int W = NT * 4;
    const int col = lane & 15, ksub = lane >> 4;
    const int row = wave * 16 + col;
    const __hip_bfloat16* __restrict__ a1 = A1 + ksub * 2048 + row * 8;
    const __hip_bfloat16* __restrict__ a2 = A2 + ksub * 2048 + (A2W4 ? row * 4 : row * 8);

    short8 rb[4];
#pragma unroll
    for (int i = 0; i < 4; ++i) rb[i] = afrag8(a1, i);   // NK1 >= 16 always

    floatx4 acc[NT];
#pragma unroll
    for (int ti = 0; ti < NT; ++ti) acc[ti] = (floatx4){0.f, 0.f, 0.f, 0.f};

#pragma unroll 4
    for (int kc = 0; kc < NK; ++kc) {
#pragma unroll
        for (int ti = 0; ti < NT; ++ti)
            acc[ti] = __builtin_amdgcn_mfma_f32_16x16x32_bf16(
                rb[kc & 3], ldsw[bslot0 + ti * TSTR + kc * 64], acc[ti], 0, 0, 0);
        int kn = kc + 4;
        if (kn < NK)
            rb[kc & 3] = (kn < NK1) ? afrag8(a1, kn)
                        : (A2W4 ? afrag4(a2, kn - NK1) : afrag8(a2, kn - NK1));
    }

    // epilogue: C/D layout col=lane&15, row=(lane>>4)*4+r. Gates at cols 4*g+du.
    const int du = col & 3;
    const int sbase = ksub * 16 + du;
#pragma unroll
    for (int ti = 0; ti < NT; ++ti) {
        float avb[4];
#pragma unroll
        for (int r = 0; r < 4; ++r) avb[r] = acc[ti][r] + bl[ti];
#pragma unroll
        for (int r = 0; r < 4; ++r) {
            float gI = __shfl(avb[r], sbase);
            float gF = __shfl(avb[r], sbase + 4);
            float gG = __shfl(avb[r], sbase + 8);
            float gO = __shfl(avb[r], sbase + 12);
            float i_ = fsig(gI), f_ = fsig(gF), gg = ftanh(gG), o_ = fsig(gO);
            float cn = f_ * creg[ti][r] + i_ * gg;
            creg[ti][r] = cn;
            float hn = o_ * ftanh(cn);
            if (col < 4) {
                int orow = wave * 16 + ksub * 4 + r;
                hs[((size_t)slab * 256 + orow) * W + ti * 4 + du] = __float2bfloat16(hn);
                if (fin) {
                    int unit = (tbase + ti) * 4 + du;
                    ho[(size_t)orow * H + unit] = hn;
                    co[(size_t)orow * H + unit] = cn;
                }
            }
        }
    }
}

// ---------------- persistent kernel ----------------
__global__ __launch_bounds__(NTHR, 4) void lstm_persistent(
    const __hip_bfloat16* __restrict__ xs,
    const __hip_bfloat16* __restrict__ w1f,
    const __hip_bfloat16* __restrict__ w2f,
    const __hip_bfloat16* __restrict__ w3f,
    const float* __restrict__ bc1, const float* __restrict__ bc2, const float* __restrict__ bc3,
    __hip_bfloat16* __restrict__ h1b, __hip_bfloat16* __restrict__ h2b,
    __hip_bfloat16* __restrict__ h3b,
    float* __restrict__ out, int* syncp)
{
    __shared__ short8 ldsw[9216];   // A: w2 2 tiles [0,8192). B: w1 2 tiles [0,6144) + w3 1 tile [6144,9216)
    const int tid = threadIdx.x, blk = blockIdx.x;
    const int lane = tid & 63, wave = tid >> 6;
    const bool isA = blk < 128;
    const int sb = isA ? blk : (blk - 128);   // group-local slab index

    if (isA) {
        const short8* s2 = (const short8*)w2f + (size_t)sb * 8192;
        for (int i = tid; i < 8192; i += NTHR) ldsw[i] = s2[i];
    } else {
        const short8* s1 = (const short8*)w1f + (size_t)sb * 6144;
        for (int i = tid; i < 6144; i += NTHR) ldsw[i] = s1[i];
        const short8* s3 = (const short8*)w3f + (size_t)sb * 3072;
        for (int i = tid; i < 3072; i += NTHR) ldsw[6144 + i] = s3[i];
    }
    __syncthreads();

    const int col = lane & 15, ksub = lane >> 4, du = col & 3, g = col >> 2;

    float bl1[2], bl2[2], bl3[1];
    if (isA) {
        bl2[0] = bc2[g * 1024 + (2 * sb + 0) * 4 + du];
        bl2[1] = bc2[g * 1024 + (2 * sb + 1) * 4 + du];
        bl1[0] = bl1[1] = bl3[0] = 0.f;
    } else {
        bl1[0] = bc1[g * 1024 + (2 * sb + 0) * 4 + du];
        bl1[1] = bc1[g * 1024 + (2 * sb + 1) * 4 + du];
        bl3[0] = bc3[g * 512 + sb * 4 + du];
        bl2[0] = bl2[1] = 0.f;
    }

    float c1r[2][4] = {{0.f,0.f,0.f,0.f},{0.f,0.f,0.f,0.f}};
    float c2r[2][4] = {{0.f,0.f,0.f,0.f},{0.f,0.f,0.f,0.f}};
    float c3r[1][4] = {{0.f,0.f,0.f,0.f}};

    float* h1o = out;
    float* c1o = out + 262144;
    float* h2o = out + 524288;
    float* c2o = out + 786432;
    float* h3o = out + 1048576;
    float* c3o = out + 1179648;

    // prologue: group B runs l1(0): A=[x(0) | h1(-1)=0(buf1)] -> h1(0) buf0
    if (!isA) {
        run_layer<16, 32, false, 2, 1024, 3072>(ldsw, lane,
            xs, h1b + 262144, bl1, h1b, sb, c1r, 2 * sb, lane, wave, false, h1o, c1o);
    }
    grid_sync(syncp);

    // phase(t): groupA: l2(t); groupB: l1(t+1), l3(t-1); barrier
    for (int t = 0; t < 128; ++t) {
        const size_t cur = (size_t)(t & 1), prv = (size_t)((t + 1) & 1);
        if (isA) {
            // l2(t): A=[h1(t) | h2(t-1)] -> h2(t)
            run_layer<32, 32, false, 2, 1024, 4096>(ldsw, lane,
                h1b + cur * 262144, h2b + prv * 262144, bl2,
                h2b + cur * 262144, sb, c2r, 2 * sb, lane, wave, t == 127, h2o, c2o);
        } else {
            // l1(t+1): A=[x(t+1) | h1(t)] -> h1(t+1)
            if (t < 127) {
                run_layer<16, 32, false, 2, 1024, 3072>(ldsw, lane,
                    xs + (size_t)(t + 1) * 131072, h1b + cur * 262144, bl1,
                    h1b + prv * 262144, sb, c1r, 2 * sb, lane, wave, (t + 1) == 127, h1o, c1o);
            }
            // l3(t-1): A=[h2(t-1) | h3(t-2)] -> h3(t-1)
            if (t >= 1) {
                run_layer<32, 16, true, 1, 512, 0>(ldsw, 6144 + lane,
                    h2b + prv * 262144, h3b + cur * 131072, bl3,
                    h3b + prv * 131072, sb, c3r, sb, lane, wave, false, h3o, c3o);
            }
        }
        grid_sync(syncp);
    }

    // epilogue: group B: l3(127): A=[h2(127)(buf1) | h3(126)(buf0)] -> h3(127), final
    if (!isA) {
        run_layer<32, 16, true, 1, 512, 0>(ldsw, 6144 + lane,
            h2b + 262144, h3b, bl3, h3b + 131072, sb, c3r, sb, lane, wave, true, h3o, c3o);
    }
}

// ---------------- launch ----------------
extern "C" void kernel_launch(void* const* d_in, const int* in_sizes, int n_in,
                              void* d_out, int out_size, void* d_ws, size_t ws_size,
                              hipStream_t stream) {
    const float* x    = (const float*)d_in[0];
    const float* Wih1 = (const float*)d_in[1];
    const float* Whh1 = (const float*)d_in[2];
    const float* bih1 = (const float*)d_in[3];
    const float* bhh1 = (const float*)d_in[4];
    const float* Wih2 = (const float*)d_in[5];
    const float* Whh2 = (const float*)d_in[6];
    const float* bih2 = (const float*)d_in[7];
    const float* bhh2 = (const float*)d_in[8];
    const float* Wih3 = (const float*)d_in[9];
    const float* Whh3 = (const float*)d_in[10];
    const float* bih3 = (const float*)d_in[11];
    const float* bhh3 = (const float*)d_in[12];
    float* out = (float*)d_out;

    char* p = (char*)d_ws;
    auto alloc = [&](size_t bytes) {
        char* r = p;
        p += (bytes + 255) & ~(size_t)255;
        return r;
    };
    __hip_bfloat16* xs  = (__hip_bfloat16*)alloc((size_t)128 * 64 * 256 * 8 * 2);  // 33.55 MB
    __hip_bfloat16* w1f = (__hip_bfloat16*)alloc((size_t)256 * 48 * 64 * 8 * 2);   // 12.58 MB
    __hip_bfloat16* w2f = (__hip_bfloat16*)alloc((size_t)256 * 64 * 64 * 8 * 2);   // 16.78 MB
    __hip_bfloat16* w3f = (__hip_bfloat16*)alloc((size_t)128 * 48 * 64 * 8 * 2);   // 6.29 MB
    float* bc1 = (float*)alloc(4096 * 4);
    float* bc2 = (float*)alloc(4096 * 4);
    float* bc3 = (float*)alloc(2048 * 4);
    __hip_bfloat16* h1b = (__hip_bfloat16*)alloc((size_t)2 * 262144 * 2);
    __hip_bfloat16* h2b = (__hip_bfloat16*)alloc((size_t)2 * 262144 * 2);
    __hip_bfloat16* h3b = (__hip_bfloat16*)alloc((size_t)2 * 131072 * 2);
    int* syncp = (int*)alloc(4096);

    auto blocks = [](int n) { return (n + 255) / 256; };

    pack_frag_kernel<512, 1024, 1024><<<blocks(256 * 48 * 64), 256, 0, stream>>>(Wih1, Whh1, w1f);
    pack_frag_kernel<1024, 1024, 1024><<<blocks(256 * 64 * 64), 256, 0, stream>>>(Wih2, Whh2, w2f);
    pack_frag_kernel<1024, 512, 512><<<blocks(128 * 48 * 64), 256, 0, stream>>>(Wih3, Whh3, w3f);
    pack_bias_kernel<<<blocks(4096), 256, 0, stream>>>(bih1, bhh1, 4096, bc1);
    pack_bias_kernel<<<blocks(4096), 256, 0, stream>>>(bih2, bhh2, 4096, bc2);
    pack_bias_kernel<<<blocks(2048), 256, 0, stream>>>(bih3, bhh3, 2048, bc3);
    x_to_slab_kernel<<<blocks(128 * 256 * 512), 256, 0, stream>>>(x, xs);
    zero_f32_kernel<<<blocks(262144), 256, 0, stream>>>((float*)h1b, 262144);
    zero_f32_kernel<<<blocks(262144), 256, 0, stream>>>((float*)h2b, 262144);
    zero_f32_kernel<<<blocks(131072), 256, 0, stream>>>((float*)h3b, 131072);
    zero_i32_kernel<<<1, 1024, 0, stream>>>(syncp, 1024);

    lstm_persistent<<<NBLK, NTHR, 0, stream>>>(xs, w1f, w2f, w3f, bc1, bc2, bc3,
                                               h1b, h2b, h3b, out, syncp);
}

// Round 7
// 4005.155 us; speedup vs baseline: 2.2064x; 2.2064x over previous
//
#include <hip/hip_runtime.h>
#include <hip/hip_bf16.h>
#include <cstdint>
#include <cstddef>

// 3-layer LSTM (T=128, B=256, IN=512, H=1024/1024/512) — persistent kernel, round 7.
// vs round 6 (8.84 ms, phase time invariant to work distribution => barrier-bound):
//  - FENCE-DISCIPLINED BARRIER: relaxed spin (no buffer_inv per poll), arrival adds
//    relaxed (syncthreads already drained stores to L2), agent-release fence
//    (buffer_wbl2) only by the per-XCD group closer -> 9 wbl2/phase instead of 256+,
//    zero L2-invalidation storms while spinning. One acquire fence per block on exit.
//  - XCD identity via s_getreg(HW_REG_XCC_ID) (m09); per-XCD arrival counts censused
//    at runtime (robust to uneven block->XCD assignment).
//  - Compute structure unchanged from round 6 (layer-specialized groups, 2 N-tiles,
//    8-wide slabs, depth-4 ring, unroll 4 — proven no-spill).

typedef __attribute__((ext_vector_type(8))) short short8;
typedef __attribute__((ext_vector_type(4))) short short4v;
typedef __attribute__((ext_vector_type(4))) float floatx4;

#define NBLK 256
#define NTHR 1024

// ---------------- helpers ----------------
__device__ __forceinline__ float fsig(float x) {
    x = fminf(fmaxf(x, -30.f), 30.f);
    return 1.f / (1.f + __expf(-x));
}
__device__ __forceinline__ float ftanh(float x) {
    x = fminf(fmaxf(x, -15.f), 15.f);
    float e = __expf(2.f * x);
    return (e - 1.f) / (e + 1.f);
}

__device__ __forceinline__ int get_xcc() {
    int x;
    asm volatile("s_getreg_b32 %0, hwreg(HW_REG_XCC_ID)" : "=s"(x));
    return x & 7;
}

// sy layout (ints): xcc arrival counters @ x*64 (x<8); master @512; gen @576;
// census @640+x; safe-barrier arrival @704; safe-barrier flag @768.

// One-time safe barrier (no XCD assumptions).
__device__ __forceinline__ void safe_sync(int* sy) {
    __syncthreads();
    if (threadIdx.x == 0) {
        int a = __hip_atomic_fetch_add(sy + 704, 1, __ATOMIC_ACQ_REL, __HIP_MEMORY_SCOPE_AGENT);
        if (a == NBLK - 1)
            __hip_atomic_store(sy + 768, 1, __ATOMIC_RELEASE, __HIP_MEMORY_SCOPE_AGENT);
        while (__hip_atomic_load(sy + 768, __ATOMIC_RELAXED, __HIP_MEMORY_SCOPE_AGENT) == 0)
            __builtin_amdgcn_s_sleep(2);
        __builtin_amdgcn_fence(__ATOMIC_ACQUIRE, "agent");
    }
    __syncthreads();
}

// Phase barrier. Entry __syncthreads drains every wave's stores to the local L2
// (compiler emits s_waitcnt vmcnt(0) before s_barrier). Arrival adds are relaxed;
// the per-XCD closer's agent-release fence (buffer_wbl2) publishes the whole XCD's
// drained stores. Spin is relaxed; single agent-acquire fence (buffer_inv) on exit.
__device__ __forceinline__ void grid_sync(int* sy, int myx, int myM, int G) {
    __syncthreads();
    if (threadIdx.x == 0) {
        int* gen = sy + 576;
        int g = __hip_atomic_load(gen, __ATOMIC_RELAXED, __HIP_MEMORY_SCOPE_AGENT);
        int a = __hip_atomic_fetch_add(sy + myx * 64, 1, __ATOMIC_RELAXED, __HIP_MEMORY_SCOPE_AGENT);
        if ((a + 1) % myM == 0) {
            __builtin_amdgcn_fence(__ATOMIC_RELEASE, "agent");   // wbl2: publish this XCD
            int m = __hip_atomic_fetch_add(sy + 512, 1, __ATOMIC_RELAXED, __HIP_MEMORY_SCOPE_AGENT);
            if ((m + 1) % G == 0)
                __hip_atomic_fetch_add(gen, 1, __ATOMIC_RELEASE, __HIP_MEMORY_SCOPE_AGENT);
        }
        while (__hip_atomic_load(gen, __ATOMIC_RELAXED, __HIP_MEMORY_SCOPE_AGENT) == g)
            __builtin_amdgcn_s_sleep(2);
        __builtin_amdgcn_fence(__ATOMIC_ACQUIRE, "agent");       // inv: see other XCDs
    }
    __syncthreads();
}

// ---------------- pack kernels ----------------
// Frag-ordered weight pack: dst[tile][kc][slot] of short8, 16 cols per tile.
// slot = lane: du=slot&3, g=(slot>>2)&3, ksub=slot>>4. unit = tile*4+du.
template<int K1, int K2, int H>
__global__ void pack_frag_kernel(const float* __restrict__ Wih,
                                 const float* __restrict__ Whh,
                                 __hip_bfloat16* __restrict__ dst) {
    constexpr int NK = (K1 + K2) / 32;
    constexpr int NTT = H / 4;
    int idx = blockIdx.x * 256 + threadIdx.x;
    if (idx >= NTT * NK * 64) return;
    int slot = idx & 63;
    int kc = (idx >> 6) % NK;
    int b = idx / (64 * NK);
    int du = slot & 3, g = (slot >> 2) & 3, ksub = slot >> 4;
    int unit = b * 4 + du;
    int j = g * H + unit;
    int k0 = kc * 32 + ksub * 8;
    __hip_bfloat16 tmp[8];
#pragma unroll
    for (int e = 0; e < 8; ++e) {
        int k = k0 + e;
        float v = (k < K1) ? Wih[(size_t)j * K1 + k] : Whh[(size_t)j * K2 + (k - K1)];
        tmp[e] = __float2bfloat16(v);
    }
    *(short8*)(dst + (size_t)idx * 8) = *(short8*)tmp;
}

__global__ void pack_bias_kernel(const float* __restrict__ a,
                                 const float* __restrict__ b,
                                 int n, float* __restrict__ out) {
    int i = blockIdx.x * 256 + threadIdx.x;
    if (i < n) out[i] = a[i] + b[i];
}

// x[t][row][512] fp32 -> xs[t][s 0..63][row][8] bf16 (8-wide slabs).
__global__ void x_to_slab_kernel(const float* __restrict__ x,
                                 __hip_bfloat16* __restrict__ xs) {
    int idx = blockIdx.x * 256 + threadIdx.x;
    int j   = idx & 7;
    int row = (idx >> 3) & 255;
    int s   = (idx >> 11) & 63;
    int t   = idx >> 17;
    xs[idx] = __float2bfloat16(x[((size_t)(t * 256 + row)) * 512 + s * 8 + j]);
}

__global__ void zero_f32_kernel(float* p, int n) {
    int i = blockIdx.x * 256 + threadIdx.x;
    if (i < n) p[i] = 0.f;
}

__global__ void zero_i32_kernel(int* p, int n) {
    int i = blockIdx.x * 256 + threadIdx.x;
    if (i < n) p[i] = 0;
}

// ---------------- A-fragment loaders ----------------
__device__ __forceinline__ short8 afrag8(const __hip_bfloat16* __restrict__ base, int k) {
    return *(const short8*)(base + (size_t)k * 8192);
}
__device__ __forceinline__ short8 afrag4(const __hip_bfloat16* __restrict__ base, int k) {
    const __hip_bfloat16* p = base + (size_t)k * 8192;
    short4v lo = *(const short4v*)p;
    short4v hi = *(const short4v*)(p + 1024);
    return (short8){lo.x, lo.y, lo.z, lo.w, hi.x, hi.y, hi.z, hi.w};
}

// ---------------- per-layer GEMM + fused cell ----------------
template<int NK1, int NK2, bool A2W4, int NT, int H, int TSTR>
__device__ __forceinline__ void run_layer(
    const short8* __restrict__ ldsw, int bslot0,
    const __hip_bfloat16* __restrict__ A1, const __hip_bfloat16* __restrict__ A2,
    const float (&bl)[NT],
    __hip_bfloat16* __restrict__ hs, int slab,
    float (&creg)[NT][4], int tbase, int lane, int wave,
    bool fin, float* __restrict__ ho, float* __restrict__ co)
{
    constexpr int NK = NK1 + NK2;
    constexpr int W = NT * 4;
    const int col = lane & 15, ksub = lane >> 4;
    const int row = wave * 16 + col;
    const __hip_bfloat16* __restrict__ a1 = A1 + ksub * 2048 + row * 8;
    const __hip_bfloat16* __restrict__ a2 = A2 + ksub * 2048 + (A2W4 ? row * 4 : row * 8);

    short8 rb[4];
#pragma unroll
    for (int i = 0; i < 4; ++i) rb[i] = afrag8(a1, i);   // NK1 >= 16 always

    floatx4 acc[NT];
#pragma unroll
    for (int ti = 0; ti < NT; ++ti) acc[ti] = (floatx4){0.f, 0.f, 0.f, 0.f};

#pragma unroll 4
    for (int kc = 0; kc < NK; ++kc) {
#pragma unroll
        for (int ti = 0; ti < NT; ++ti)
            acc[ti] = __builtin_amdgcn_mfma_f32_16x16x32_bf16(
                rb[kc & 3], ldsw[bslot0 + ti * TSTR + kc * 64], acc[ti], 0, 0, 0);
        int kn = kc + 4;
        if (kn < NK)
            rb[kc & 3] = (kn < NK1) ? afrag8(a1, kn)
                        : (A2W4 ? afrag4(a2, kn - NK1) : afrag8(a2, kn - NK1));
    }

    // epilogue: C/D layout col=lane&15, row=(lane>>4)*4+r. Gates at cols 4*g+du.
    const int du = col & 3;
    const int sbase = ksub * 16 + du;
#pragma unroll
    for (int ti = 0; ti < NT; ++ti) {
        float avb[4];
#pragma unroll
        for (int r = 0; r < 4; ++r) avb[r] = acc[ti][r] + bl[ti];
#pragma unroll
        for (int r = 0; r < 4; ++r) {
            float gI = __shfl(avb[r], sbase);
            float gF = __shfl(avb[r], sbase + 4);
            float gG = __shfl(avb[r], sbase + 8);
            float gO = __shfl(avb[r], sbase + 12);
            float i_ = fsig(gI), f_ = fsig(gF), gg = ftanh(gG), o_ = fsig(gO);
            float cn = f_ * creg[ti][r] + i_ * gg;
            creg[ti][r] = cn;
            float hn = o_ * ftanh(cn);
            if (col < 4) {
                int orow = wave * 16 + ksub * 4 + r;
                hs[((size_t)slab * 256 + orow) * W + ti * 4 + du] = __float2bfloat16(hn);
                if (fin) {
                    int unit = (tbase + ti) * 4 + du;
                    ho[(size_t)orow * H + unit] = hn;
                    co[(size_t)orow * H + unit] = cn;
                }
            }
        }
    }
}

// ---------------- persistent kernel ----------------
__global__ __launch_bounds__(NTHR, 4) void lstm_persistent(
    const __hip_bfloat16* __restrict__ xs,
    const __hip_bfloat16* __restrict__ w1f,
    const __hip_bfloat16* __restrict__ w2f,
    const __hip_bfloat16* __restrict__ w3f,
    const float* __restrict__ bc1, const float* __restrict__ bc2, const float* __restrict__ bc3,
    __hip_bfloat16* __restrict__ h1b, __hip_bfloat16* __restrict__ h2b,
    __hip_bfloat16* __restrict__ h3b,
    float* __restrict__ out, int* syncp)
{
    __shared__ short8 ldsw[9216];   // A: w2 2 tiles [0,8192). B: w1 2 tiles [0,6144) + w3 [6144,9216)
    const int tid = threadIdx.x, blk = blockIdx.x;
    const int lane = tid & 63, wave = tid >> 6;
    const bool isA = blk < 128;
    const int sb = isA ? blk : (blk - 128);

    if (isA) {
        const short8* s2 = (const short8*)w2f + (size_t)sb * 8192;
        for (int i = tid; i < 8192; i += NTHR) ldsw[i] = s2[i];
    } else {
        const short8* s1 = (const short8*)w1f + (size_t)sb * 6144;
        for (int i = tid; i < 6144; i += NTHR) ldsw[i] = s1[i];
        const short8* s3 = (const short8*)w3f + (size_t)sb * 3072;
        for (int i = tid; i < 3072; i += NTHR) ldsw[6144 + i] = s3[i];
    }

    // census: discover this block's XCD and per-XCD arrival counts
    int myx = 0, myM = 1, G = 1;
    if (tid == 0) {
        myx = get_xcc();
        __hip_atomic_fetch_add(syncp + 640 + myx, 1, __ATOMIC_RELAXED, __HIP_MEMORY_SCOPE_AGENT);
    }
    safe_sync(syncp);
    if (tid == 0) {
        myM = __hip_atomic_load(syncp + 640 + myx, __ATOMIC_RELAXED, __HIP_MEMORY_SCOPE_AGENT);
        G = 0;
        for (int x = 0; x < 8; ++x)
            G += (__hip_atomic_load(syncp + 640 + x, __ATOMIC_RELAXED, __HIP_MEMORY_SCOPE_AGENT) > 0);
        if (myM < 1) myM = 1;
        if (G < 1) G = 1;
    }
    __syncthreads();

    const int col = lane & 15, ksub = lane >> 4, du = col & 3, g = col >> 2;
    (void)ksub; (void)col;

    float bl1[2], bl2[2], bl3[1];
    if (isA) {
        bl2[0] = bc2[g * 1024 + (2 * sb + 0) * 4 + du];
        bl2[1] = bc2[g * 1024 + (2 * sb + 1) * 4 + du];
        bl1[0] = bl1[1] = bl3[0] = 0.f;
    } else {
        bl1[0] = bc1[g * 1024 + (2 * sb + 0) * 4 + du];
        bl1[1] = bc1[g * 1024 + (2 * sb + 1) * 4 + du];
        bl3[0] = bc3[g * 512 + sb * 4 + du];
        bl2[0] = bl2[1] = 0.f;
    }

    float c1r[2][4] = {{0.f,0.f,0.f,0.f},{0.f,0.f,0.f,0.f}};
    float c2r[2][4] = {{0.f,0.f,0.f,0.f},{0.f,0.f,0.f,0.f}};
    float c3r[1][4] = {{0.f,0.f,0.f,0.f}};

    float* h1o = out;
    float* c1o = out + 262144;
    float* h2o = out + 524288;
    float* c2o = out + 786432;
    float* h3o = out + 1048576;
    float* c3o = out + 1179648;

    // prologue: group B runs l1(0): A=[x(0) | h1(-1)=0(buf1)] -> h1(0) buf0
    if (!isA) {
        run_layer<16, 32, false, 2, 1024, 3072>(ldsw, lane,
            xs, h1b + 262144, bl1, h1b, sb, c1r, 2 * sb, lane, wave, false, h1o, c1o);
    }
    grid_sync(syncp, myx, myM, G);

    // phase(t): groupA: l2(t); groupB: l1(t+1), l3(t-1); barrier
    for (int t = 0; t < 128; ++t) {
        const size_t cur = (size_t)(t & 1), prv = (size_t)((t + 1) & 1);
        if (isA) {
            run_layer<32, 32, false, 2, 1024, 4096>(ldsw, lane,
                h1b + cur * 262144, h2b + prv * 262144, bl2,
                h2b + cur * 262144, sb, c2r, 2 * sb, lane, wave, t == 127, h2o, c2o);
        } else {
            if (t < 127) {
                run_layer<16, 32, false, 2, 1024, 3072>(ldsw, lane,
                    xs + (size_t)(t + 1) * 131072, h1b + cur * 262144, bl1,
                    h1b + prv * 262144, sb, c1r, 2 * sb, lane, wave, (t + 1) == 127, h1o, c1o);
            }
            if (t >= 1) {
                run_layer<32, 16, true, 1, 512, 0>(ldsw, 6144 + lane,
                    h2b + prv * 262144, h3b + cur * 131072, bl3,
                    h3b + prv * 131072, sb, c3r, sb, lane, wave, false, h3o, c3o);
            }
        }
        grid_sync(syncp, myx, myM, G);
    }

    // epilogue: group B: l3(127): A=[h2(127)(buf1) | h3(126)(buf0)] -> h3(127), final
    if (!isA) {
        run_layer<32, 16, true, 1, 512, 0>(ldsw, 6144 + lane,
            h2b + 262144, h3b, bl3, h3b + 131072, sb, c3r, sb, lane, wave, true, h3o, c3o);
    }
}

// ---------------- launch ----------------
extern "C" void kernel_launch(void* const* d_in, const int* in_sizes, int n_in,
                              void* d_out, int out_size, void* d_ws, size_t ws_size,
                              hipStream_t stream) {
    const float* x    = (const float*)d_in[0];
    const float* Wih1 = (const float*)d_in[1];
    const float* Whh1 = (const float*)d_in[2];
    const float* bih1 = (const float*)d_in[3];
    const float* bhh1 = (const float*)d_in[4];
    const float* Wih2 = (const float*)d_in[5];
    const float* Whh2 = (const float*)d_in[6];
    const float* bih2 = (const float*)d_in[7];
    const float* bhh2 = (const float*)d_in[8];
    const float* Wih3 = (const float*)d_in[9];
    const float* Whh3 = (const float*)d_in[10];
    const float* bih3 = (const float*)d_in[11];
    const float* bhh3 = (const float*)d_in[12];
    float* out = (float*)d_out;

    char* p = (char*)d_ws;
    auto alloc = [&](size_t bytes) {
        char* r = p;
        p += (bytes + 255) & ~(size_t)255;
        return r;
    };
    __hip_bfloat16* xs  = (__hip_bfloat16*)alloc((size_t)128 * 64 * 256 * 8 * 2);
    __hip_bfloat16* w1f = (__hip_bfloat16*)alloc((size_t)256 * 48 * 64 * 8 * 2);
    __hip_bfloat16* w2f = (__hip_bfloat16*)alloc((size_t)256 * 64 * 64 * 8 * 2);
    __hip_bfloat16* w3f = (__hip_bfloat16*)alloc((size_t)128 * 48 * 64 * 8 * 2);
    float* bc1 = (float*)alloc(4096 * 4);
    float* bc2 = (float*)alloc(4096 * 4);
    float* bc3 = (float*)alloc(2048 * 4);
    __hip_bfloat16* h1b = (__hip_bfloat16*)alloc((size_t)2 * 262144 * 2);
    __hip_bfloat16* h2b = (__hip_bfloat16*)alloc((size_t)2 * 262144 * 2);
    __hip_bfloat16* h3b = (__hip_bfloat16*)alloc((size_t)2 * 131072 * 2);
    int* syncp = (int*)alloc(4096);

    auto blocks = [](int n) { return (n + 255) / 256; };

    pack_frag_kernel<512, 1024, 1024><<<blocks(256 * 48 * 64), 256, 0, stream>>>(Wih1, Whh1, w1f);
    pack_frag_kernel<1024, 1024, 1024><<<blocks(256 * 64 * 64), 256, 0, stream>>>(Wih2, Whh2, w2f);
    pack_frag_kernel<1024, 512, 512><<<blocks(128 * 48 * 64), 256, 0, stream>>>(Wih3, Whh3, w3f);
    pack_bias_kernel<<<blocks(4096), 256, 0, stream>>>(bih1, bhh1, 4096, bc1);
    pack_bias_kernel<<<blocks(4096), 256, 0, stream>>>(bih2, bhh2, 4096, bc2);
    pack_bias_kernel<<<blocks(2048), 256, 0, stream>>>(bih3, bhh3, 2048, bc3);
    x_to_slab_kernel<<<blocks(128 * 256 * 512), 256, 0, stream>>>(x, xs);
    zero_f32_kernel<<<blocks(262144), 256, 0, stream>>>((float*)h1b, 262144);
    zero_f32_kernel<<<blocks(262144), 256, 0, stream>>>((float*)h2b, 262144);
    zero_f32_kernel<<<blocks(131072), 256, 0, stream>>>((float*)h3b, 131072);
    zero_i32_kernel<<<1, 1024, 0, stream>>>(syncp, 1024);

    lstm_persistent<<<NBLK, NTHR, 0, stream>>>(xs, w1f, w2f, w3f, bc1, bc2, bc3,
                                               h1b, h2b, h3b, out, syncp);
}